// Round 6
// baseline (273.269 us; speedup 1.0000x reference)
//
#include <hip/hip_runtime.h>
#include <hip/hip_bf16.h>

#define ALPHA   0.1f
#define S_DECAY 0.95f
#define P_DECAY 0.99f
#define D_EMB   768
#define DK      256

// ---- DPP wave-64 reduction helpers (validated rounds 1-5) ----
template<int ctrl, int row_mask>
__device__ __forceinline__ float dpp_add(float x) {
    int y = __builtin_amdgcn_update_dpp(0, __float_as_int(x), ctrl, row_mask, 0xF, true);
    return x + __int_as_float(y);
}

template<int N>
__device__ __forceinline__ void wave_allred_arr(float (&x)[N]) {
#pragma unroll
    for (int n = 0; n < N; ++n) x[n] = dpp_add<0xB1,  0xF>(x[n]);
#pragma unroll
    for (int n = 0; n < N; ++n) x[n] = dpp_add<0x4E,  0xF>(x[n]);
#pragma unroll
    for (int n = 0; n < N; ++n) x[n] = dpp_add<0x141, 0xF>(x[n]);
#pragma unroll
    for (int n = 0; n < N; ++n) x[n] = dpp_add<0x140, 0xF>(x[n]);
#pragma unroll
    for (int n = 0; n < N; ++n) x[n] = dpp_add<0x142, 0xA>(x[n]);
#pragma unroll
    for (int n = 0; n < N; ++n) x[n] = dpp_add<0x143, 0xC>(x[n]);
#pragma unroll
    for (int n = 0; n < N; ++n)
        x[n] = __int_as_float(__builtin_amdgcn_readlane(__float_as_int(x[n]), 63));
}

__device__ __forceinline__ float dot4v(const float4& a, const float4& b) {
    float t0 = a.x * b.x; t0 = fmaf(a.y, b.y, t0);
    float t1 = a.z * b.z; t1 = fmaf(a.w, b.w, t1);
    return t0 + t1;
}

__device__ __forceinline__ float rl(float x, int lane) {
    return __int_as_float(__builtin_amdgcn_readlane(__float_as_int(x), lane));
}

#define REP10(X) X(0) X(1) X(2) X(3) X(4) X(5) X(6) X(7) X(8) X(9)

// ---------------- Kernel 1: prep = GEMM (10 rows/block, depth-2 W pipeline)
//   + K row norms -> USrev + paragraph means/norms + SVv + pad zero + out zero ----------
__global__ __launch_bounds__(256) void prep_kernel(
    const float* __restrict__ emb,
    const float* __restrict__ Wk, const float* __restrict__ bk,
    const float* __restrict__ Wv, const float* __restrict__ bv,
    float* __restrict__ V, float* __restrict__ PV,
    float* __restrict__ USrev, float* __restrict__ UPrev, float* __restrict__ UPfwd,
    float* __restrict__ SVv, float* __restrict__ out,
    int T, int P, int PADS, int PADP)
{
    const int tid = threadIdx.x;
    const int blk = blockIdx.x;
    const int NB = P / 2;                       // 100 compute blocks
    if (blk >= NB) {
        // pad zeroing block
        int nS = (PADS - T) * DK;
        for (int i = tid; i < nS; i += 256) USrev[(size_t)T * DK + i] = 0.f;
        int nP = (PADP - P) * DK;
        for (int i = tid; i < nP; i += 256) {
            UPrev[(size_t)P * DK + i] = 0.f;
            UPfwd[(size_t)P * DK + i] = 0.f;
            PV[(size_t)P * DK + i]    = 0.f;
        }
        for (int i = tid; i < PADP - P; i += 256) SVv[P + i] = 0.f;
        out[tid] = 0.f;
        return;
    }

    __shared__ float se[10][D_EMB];
    __shared__ float s_red[4][14];
    const int j = tid, wave = tid >> 6, l = tid & 63;
    const int r0 = blk * 10;

    for (int i = tid; i < 10 * D_EMB; i += 256) {
        int r = i / D_EMB, d = i - r * D_EMB;
        se[r][d] = emb[(size_t)(r0 + r) * D_EMB + d];
    }
    __syncthreads();

    const float* wkp = Wk + j;
    const float* wvp = Wv + j;

#define DECL_ACC(n) float ak##n = 0.f, av##n = 0.f;
    REP10(DECL_ACC)

    // depth-2 W pipeline: cur (d), pend (d+4)
    float a0 = wkp[0*DK], a1 = wkp[1*DK], a2 = wkp[2*DK], a3 = wkp[3*DK];
    float b0 = wvp[0*DK], b1 = wvp[1*DK], b2 = wvp[2*DK], b3 = wvp[3*DK];
    float pa0 = wkp[4*DK], pa1 = wkp[5*DK], pa2 = wkp[6*DK], pa3 = wkp[7*DK];
    float pb0 = wvp[4*DK], pb1 = wvp[5*DK], pb2 = wvp[6*DK], pb3 = wvp[7*DK];

    for (int d = 0; d < D_EMB; d += 4) {
        int dn = d + 8; if (dn >= D_EMB) dn = 0;
        const float* wk2 = wkp + (size_t)dn * DK;
        const float* wv2 = wvp + (size_t)dn * DK;
        float qa0 = wk2[0], qa1 = wk2[DK], qa2 = wk2[2*DK], qa3 = wk2[3*DK];
        float qb0 = wv2[0], qb1 = wv2[DK], qb2 = wv2[2*DK], qb3 = wv2[3*DK];

#define ELOAD(n) float4 e##n = *reinterpret_cast<const float4*>(&se[n][d]);
        REP10(ELOAD)
#define DOFMA(n) \
        ak##n = fmaf(e##n.x, a0, ak##n); ak##n = fmaf(e##n.y, a1, ak##n); \
        ak##n = fmaf(e##n.z, a2, ak##n); ak##n = fmaf(e##n.w, a3, ak##n); \
        av##n = fmaf(e##n.x, b0, av##n); av##n = fmaf(e##n.y, b1, av##n); \
        av##n = fmaf(e##n.z, b2, av##n); av##n = fmaf(e##n.w, b3, av##n);
        REP10(DOFMA)
#undef ELOAD

        a0 = pa0; a1 = pa1; a2 = pa2; a3 = pa3;
        b0 = pb0; b1 = pb1; b2 = pb2; b3 = pb3;
        pa0 = qa0; pa1 = qa1; pa2 = qa2; pa3 = qa3;
        pb0 = qb0; pb1 = qb1; pb2 = qb2; pb3 = qb3;
    }

    float bkj = bk[j], bvj = bv[j];
#define FIN(n) float kk##n = ak##n + bkj; float vv##n = av##n + bvj;
    REP10(FIN)

    // paragraph means (2 paragraphs per block)
    float pk0 = (kk0 + kk1 + kk2 + kk3 + kk4) * 0.2f;
    float pk1 = (kk5 + kk6 + kk7 + kk8 + kk9) * 0.2f;
    float pv0 = (vv0 + vv1 + vv2 + vv3 + vv4) * 0.2f;
    float pv1 = (vv5 + vv6 + vv7 + vv8 + vv9) * 0.2f;

#define VST(n) V[(size_t)(r0 + n) * DK + j] = vv##n;
    REP10(VST)
    const int p0 = blk * 2, p1 = blk * 2 + 1;
    PV[(size_t)p0 * DK + j] = pv0;
    PV[(size_t)p1 * DK + j] = pv1;

    float red[14] = { kk0*kk0, kk1*kk1, kk2*kk2, kk3*kk3, kk4*kk4,
                      kk5*kk5, kk6*kk6, kk7*kk7, kk8*kk8, kk9*kk9,
                      pk0*pk0, pk1*pk1, pv0, pv1 };
    wave_allred_arr(red);
    if (l == 0) {
#pragma unroll
        for (int n = 0; n < 14; ++n) s_red[wave][n] = red[n];
    }
    __syncthreads();
    float tot[14];
#pragma unroll
    for (int n = 0; n < 14; ++n)
        tot[n] = s_red[0][n] + s_red[1][n] + s_red[2][n] + s_red[3][n];

#define UST(n) { float inv = 1.0f / fmaxf(sqrtf(tot[n]), 1e-12f); \
                 USrev[(size_t)(T - 1 - (r0 + n)) * DK + j] = kk##n * inv; }
    REP10(UST)

    float ip0 = 1.0f / fmaxf(sqrtf(tot[10]), 1e-12f);
    float ip1 = 1.0f / fmaxf(sqrtf(tot[11]), 1e-12f);
    float u0 = pk0 * ip0, u1 = pk1 * ip1;
    UPfwd[(size_t)p0 * DK + j] = u0;
    UPfwd[(size_t)p1 * DK + j] = u1;
    UPrev[(size_t)(P - 1 - p0) * DK + j] = u0;
    UPrev[(size_t)(P - 1 - p1) * DK + j] = u1;
    if (tid == 0) { SVv[p0] = tot[12]; SVv[p1] = tot[13]; }
}

// ------------- Kernel 2: gram + in-block inversion -> AinvT + biasF -------------
// 24 blocks (NCS sentence, NCP paraB, NCP paraF), 256 threads.
__global__ __launch_bounds__(256) void graminv_kernel(
    const float* __restrict__ USrev, const float* __restrict__ UPrev,
    const float* __restrict__ UPfwd, const float* __restrict__ SVv,
    float* __restrict__ AinvT, float* __restrict__ biasF, int NCS, int NCP)
{
    __shared__ float sA[64 * 65];
    __shared__ float sX[64 * 65];
    const int bid = blockIdx.x;
    const float* U; int m, type;
    if (bid < NCS)            { type = 0; m = bid;             U = USrev; }
    else if (bid < NCS + NCP) { type = 1; m = bid - NCS;       U = UPrev; }
    else                      { type = 2; m = bid - NCS - NCP; U = UPfwd; }
    const int tid = threadIdx.x;
    const int wv = tid >> 6, l = tid & 63;
    const int tr = tid & 15, tc = tid >> 4;
    const float4* U4 = reinterpret_cast<const float4*>(U) + (size_t)m * 64 * 64;

    float svvec = SVv[m * 64 + l];   // early load (type2 bias)

    // --- gram phase: A = alpha * masked (scaled) Gram, into LDS (stride 65) ---
#pragma unroll
    for (int tile = 0; tile < 4; ++tile) {
        int ti2 = tile >> 1, tj2 = tile & 1;
        int i0 = ti2 * 32 + tr * 2, j0 = tj2 * 32 + tc * 2;
        if (ti2 == 0 && tj2 == 1) {
            sA[i0*65 + j0] = 0.f; sA[i0*65 + j0 + 1] = 0.f;
            sA[(i0+1)*65 + j0] = 0.f; sA[(i0+1)*65 + j0 + 1] = 0.f;
            continue;
        }
        float d00 = 0.f, d01 = 0.f, d10 = 0.f, d11 = 0.f;
        for (int k = 0; k < 64; ++k) {
            float4 r0 = U4[(size_t)i0 * 64 + k];
            float4 r1 = U4[(size_t)(i0 + 1) * 64 + k];
            float4 c0 = U4[(size_t)j0 * 64 + k];
            float4 c1 = U4[(size_t)(j0 + 1) * 64 + k];
            d00 = fmaf(r0.x, c0.x, d00); d00 = fmaf(r0.y, c0.y, d00);
            d00 = fmaf(r0.z, c0.z, d00); d00 = fmaf(r0.w, c0.w, d00);
            d01 = fmaf(r0.x, c1.x, d01); d01 = fmaf(r0.y, c1.y, d01);
            d01 = fmaf(r0.z, c1.z, d01); d01 = fmaf(r0.w, c1.w, d01);
            d10 = fmaf(r1.x, c0.x, d10); d10 = fmaf(r1.y, c0.y, d10);
            d10 = fmaf(r1.z, c0.z, d10); d10 = fmaf(r1.w, c0.w, d10);
            d11 = fmaf(r1.x, c1.x, d11); d11 = fmaf(r1.y, c1.y, d11);
            d11 = fmaf(r1.z, c1.z, d11); d11 = fmaf(r1.w, c1.w, d11);
        }
        float g00, g01, g10, g11;
        if (type == 2) {
            g00 = (j0     < i0    ) ? powf(P_DECAY, (float)(i0     - j0    )) * d00 : 0.f;
            g01 = (j0 + 1 < i0    ) ? powf(P_DECAY, (float)(i0     - j0 - 1)) * d01 : 0.f;
            g10 = (j0     < i0 + 1) ? powf(P_DECAY, (float)(i0 + 1 - j0    )) * d10 : 0.f;
            g11 = (j0 + 1 < i0 + 1) ? powf(P_DECAY, (float)(i0 + 1 - j0 - 1)) * d11 : 0.f;
        } else {
            g00 = (j0     < i0    ) ? d00 : 0.f;
            g01 = (j0 + 1 < i0    ) ? d01 : 0.f;
            g10 = (j0     < i0 + 1) ? d10 : 0.f;
            g11 = (j0 + 1 < i0 + 1) ? d11 : 0.f;
        }
        sA[i0*65 + j0]       = ALPHA * g00;
        sA[i0*65 + j0 + 1]   = ALPHA * g01;
        sA[(i0+1)*65 + j0]   = ALPHA * g10;
        sA[(i0+1)*65 + j0+1] = ALPHA * g11;
    }
    __syncthreads();

    // --- bias (type 2 only): bias_i = (1/alpha) * sum_j A_ij * sv_j ---
    if (type == 2 && wv == 0) {
        float dotb = 0.f;
#pragma unroll
        for (int jj = 0; jj < 64; ++jj)
            dotb = fmaf(sA[l*65 + jj], rl(svvec, jj), dotb);
        biasF[m * 64 + l] = dotb * (1.0f / ALPHA);
    }

    // --- inversion: X = (I+A)^{-1}, wave-staged forward substitution ---
    // lane l holds column l; wave wv owns rows 16wv..16wv+15 in regs x[16].
    const int base = wv * 16;
    float x[16];
#pragma unroll
    for (int r = 0; r < 16; ++r) x[r] = (base + r == l) ? 1.f : 0.f;

    for (int s = 0; s < 4; ++s) {
        if (wv == s) {
            // internal finalize (rows depend only on earlier rows of this band)
#pragma unroll
            for (int i = 1; i < 16; ++i)
#pragma unroll
                for (int jj = 0; jj < 16; ++jj)
                    if (jj < i)
                        x[i] = fmaf(-sA[(base + i)*65 + (base + jj)], x[jj], x[i]);
            // publish
#pragma unroll
            for (int r = 0; r < 16; ++r) sX[(base + r)*65 + l] = x[r];
        }
        __syncthreads();
        if (wv > s) {
#pragma unroll
            for (int i = 0; i < 16; ++i) {
                float xi = sX[(s*16 + i)*65 + l];
#pragma unroll
                for (int r = 0; r < 16; ++r)
                    x[r] = fmaf(-sA[(base + r)*65 + (s*16 + i)], xi, x[r]);
            }
        }
    }
    __syncthreads();
    // transpose store: AinvT[j*64 + i] = X[i][j]
    float* dst = AinvT + (size_t)bid * 4096;
    for (int idx = tid; idx < 4096; idx += 256) {
        int jcol = idx >> 6, irow = idx & 63;
        dst[idx] = sX[irow*65 + jcol];
    }
}

// ------------- Kernel 3: solver, 2 concurrent blocks, parallel phase-2 via Ainv -------------
__global__ __launch_bounds__(256) void solve_kernel(
    const float* __restrict__ USrev, const float* __restrict__ UPrev,
    const float* __restrict__ UPfwd, const float* __restrict__ SVv,
    const float* __restrict__ AinvT, const float* __restrict__ biasF,
    const float* __restrict__ q,
    float* __restrict__ CS, float* __restrict__ CPB1, float* __restrict__ CPB2,
    float* __restrict__ gscal, int NCS, int NCP)
{
    __shared__ float s_b1[64], s_b2[64];
    __shared__ float4 s_part[4][64], s_part2[4][64];
    __shared__ float sAinv[4096];
    __shared__ float s_powd[65];
    const int tid = threadIdx.x, wave = tid >> 6, l = tid & 63;
    const int wbase = wave * 16;
    if (tid <= 64) s_powd[tid] = powf(P_DECAY, (float)tid);

    float4 q4 = reinterpret_cast<const float4*>(q)[l];
    float qs[1] = { dot4v(q4, q4) };
    wave_allred_arr(qs);
    float qinv = 1.0f / fmaxf(sqrtf(qs[0]), 1e-12f);
    float4 qn = make_float4(q4.x * qinv, q4.y * qinv, q4.z * qinv, q4.w * qinv);
    __syncthreads();

    const float4* G4 = reinterpret_cast<const float4*>(AinvT);
    float4* sAinv4 = reinterpret_cast<float4*>(sAinv);

    if (blockIdx.x == 0) {
        // ================= sentence backward =================
        float4 w1 = qn;
        const float4* U4 = reinterpret_cast<const float4*>(USrev);
        float4 cur[16];
#pragma unroll
        for (int r = 0; r < 16; ++r) cur[r] = U4[(size_t)(wbase + r) * 64 + l];
        for (int m = 0; m < NCS; ++m) {
            float4 g0 = G4[(size_t)m * 1024 + 0*256 + tid];
            float4 g1 = G4[(size_t)m * 1024 + 1*256 + tid];
            float4 g2 = G4[(size_t)m * 1024 + 2*256 + tid];
            float4 g3 = G4[(size_t)m * 1024 + 3*256 + tid];
            float4 nxt[16];
            if (m + 1 < NCS) {
                const float4* Un = U4 + (size_t)(m + 1) * 64 * 64;
#pragma unroll
                for (int r = 0; r < 16; ++r) nxt[r] = Un[(size_t)(wbase + r) * 64 + l];
            }
            // phase 1: b = U w
#pragma unroll
            for (int g = 0; g < 4; ++g) {
                float d[4];
#pragma unroll
                for (int r = 0; r < 4; ++r) d[r] = dot4v(cur[g*4 + r], w1);
                wave_allred_arr(d);
                if (l == 0) {
                    int i0 = wbase + g*4;
                    s_b1[i0] = d[0]; s_b1[i0+1] = d[1]; s_b1[i0+2] = d[2]; s_b1[i0+3] = d[3];
                }
            }
            sAinv4[0*256 + tid] = g0;  sAinv4[1*256 + tid] = g1;
            sAinv4[2*256 + tid] = g2;  sAinv4[3*256 + tid] = g3;
            __syncthreads();
            // phase 2: c = Ainv b (each wave full c, redundant, no extra barrier)
            float bv = s_b1[l];
            float c = 0.f;
#pragma unroll
            for (int jj = 0; jj < 64; ++jj)
                c = fmaf(sAinv[jj*64 + l], rl(bv, jj), c);
            if (wave == 0) CS[m * 64 + l] = c;
            // phase 3: w -= alpha * U^T c
            float4 acc = make_float4(0.f, 0.f, 0.f, 0.f);
#pragma unroll
            for (int r = 0; r < 16; ++r) {
                float ci = rl(c, wbase + r);
                acc.x = fmaf(ci, cur[r].x, acc.x); acc.y = fmaf(ci, cur[r].y, acc.y);
                acc.z = fmaf(ci, cur[r].z, acc.z); acc.w = fmaf(ci, cur[r].w, acc.w);
            }
            s_part[wave][l] = acc;
            __syncthreads();
            float4 p0 = s_part[0][l], p1 = s_part[1][l], p2 = s_part[2][l], p3 = s_part[3][l];
            w1.x = fmaf(-ALPHA, p0.x + p1.x + p2.x + p3.x, w1.x);
            w1.y = fmaf(-ALPHA, p0.y + p1.y + p2.y + p3.y, w1.y);
            w1.z = fmaf(-ALPHA, p0.z + p1.z + p2.z + p3.z, w1.z);
            w1.w = fmaf(-ALPHA, p0.w + p1.w + p2.w + p3.w, w1.w);
            if (m + 1 < NCS) {
#pragma unroll
                for (int r = 0; r < 16; ++r) cur[r] = nxt[r];
            }
        }
    } else {
        // ================= paragraph backward (dual RHS) =================
        {
            float4 w1 = qn;
            float4 w2 = make_float4(1.f, 1.f, 1.f, 1.f);
            const float4* U4 = reinterpret_cast<const float4*>(UPrev);
            float4 cur[16];
#pragma unroll
            for (int r = 0; r < 16; ++r) cur[r] = U4[(size_t)(wbase + r) * 64 + l];
            for (int m = 0; m < NCP; ++m) {
                size_t gb = (size_t)(NCS + m) * 1024;
                float4 g0 = G4[gb + 0*256 + tid];
                float4 g1 = G4[gb + 1*256 + tid];
                float4 g2 = G4[gb + 2*256 + tid];
                float4 g3 = G4[gb + 3*256 + tid];
                float4 nxt[16];
                if (m + 1 < NCP) {
                    const float4* Un = U4 + (size_t)(m + 1) * 64 * 64;
#pragma unroll
                    for (int r = 0; r < 16; ++r) nxt[r] = Un[(size_t)(wbase + r) * 64 + l];
                }
#pragma unroll
                for (int g = 0; g < 4; ++g) {
                    float d[8];
#pragma unroll
                    for (int r = 0; r < 4; ++r) {
                        d[r]     = dot4v(cur[g*4 + r], w1);
                        d[4 + r] = dot4v(cur[g*4 + r], w2);
                    }
                    wave_allred_arr(d);
                    if (l == 0) {
                        int i0 = wbase + g*4;
#pragma unroll
                        for (int r = 0; r < 4; ++r) { s_b1[i0+r] = d[r]; s_b2[i0+r] = d[4+r]; }
                    }
                }
                sAinv4[0*256 + tid] = g0;  sAinv4[1*256 + tid] = g1;
                sAinv4[2*256 + tid] = g2;  sAinv4[3*256 + tid] = g3;
                __syncthreads();
                float bv1 = s_b1[l], bv2 = s_b2[l];
                float c1 = 0.f, c2 = 0.f;
#pragma unroll
                for (int jj = 0; jj < 64; ++jj) {
                    float a = sAinv[jj*64 + l];
                    c1 = fmaf(a, rl(bv1, jj), c1);
                    c2 = fmaf(a, rl(bv2, jj), c2);
                }
                if (wave == 0) { CPB1[m * 64 + l] = c1; CPB2[m * 64 + l] = c2; }
                float4 a1 = make_float4(0.f,0.f,0.f,0.f), a2 = make_float4(0.f,0.f,0.f,0.f);
#pragma unroll
                for (int r = 0; r < 16; ++r) {
                    float x1 = rl(c1, wbase + r), x2 = rl(c2, wbase + r);
                    a1.x = fmaf(x1, cur[r].x, a1.x); a1.y = fmaf(x1, cur[r].y, a1.y);
                    a1.z = fmaf(x1, cur[r].z, a1.z); a1.w = fmaf(x1, cur[r].w, a1.w);
                    a2.x = fmaf(x2, cur[r].x, a2.x); a2.y = fmaf(x2, cur[r].y, a2.y);
                    a2.z = fmaf(x2, cur[r].z, a2.z); a2.w = fmaf(x2, cur[r].w, a2.w);
                }
                s_part[wave][l] = a1; s_part2[wave][l] = a2;
                __syncthreads();
                float4 p0 = s_part[0][l], p1 = s_part[1][l], p2 = s_part[2][l], p3 = s_part[3][l];
                w1.x = fmaf(-ALPHA, p0.x+p1.x+p2.x+p3.x, w1.x);
                w1.y = fmaf(-ALPHA, p0.y+p1.y+p2.y+p3.y, w1.y);
                w1.z = fmaf(-ALPHA, p0.z+p1.z+p2.z+p3.z, w1.z);
                w1.w = fmaf(-ALPHA, p0.w+p1.w+p2.w+p3.w, w1.w);
                float4 r0 = s_part2[0][l], r1 = s_part2[1][l], r2 = s_part2[2][l], r3 = s_part2[3][l];
                w2.x = fmaf(-ALPHA, r0.x+r1.x+r2.x+r3.x, w2.x);
                w2.y = fmaf(-ALPHA, r0.y+r1.y+r2.y+r3.y, w2.y);
                w2.z = fmaf(-ALPHA, r0.z+r1.z+r2.z+r3.z, w2.z);
                w2.w = fmaf(-ALPHA, r0.w+r1.w+r2.w+r3.w, w2.w);
                if (m + 1 < NCP) {
#pragma unroll
                    for (int r = 0; r < 16; ++r) cur[r] = nxt[r];
                }
            }
        }
        __syncthreads();
        // ================= paragraph forward =================
        float4 y = make_float4(0.f, 0.f, 0.f, 0.f);
        {
            const float4* U4 = reinterpret_cast<const float4*>(UPfwd);
            float4 cur[16];
#pragma unroll
            for (int r = 0; r < 16; ++r) cur[r] = U4[(size_t)(wbase + r) * 64 + l];
            for (int m = 0; m < NCP; ++m) {
                size_t gb = (size_t)(NCS + NCP + m) * 1024;
                float4 g0 = G4[gb + 0*256 + tid];
                float4 g1 = G4[gb + 1*256 + tid];
                float4 g2 = G4[gb + 2*256 + tid];
                float4 g3 = G4[gb + 3*256 + tid];
                float biasv = biasF[m * 64 + l];
                float svl   = SVv[m * 64 + l];
                float4 nxt[16];
                if (m + 1 < NCP) {
                    const float4* Un = U4 + (size_t)(m + 1) * 64 * 64;
#pragma unroll
                    for (int r = 0; r < 16; ++r) nxt[r] = Un[(size_t)(wbase + r) * 64 + l];
                }
#pragma unroll
                for (int g = 0; g < 4; ++g) {
                    float d[4];
#pragma unroll
                    for (int r = 0; r < 4; ++r) d[r] = dot4v(cur[g*4 + r], y);
                    wave_allred_arr(d);
                    if (l == 0) {
                        int i0 = wbase + g*4;
                        s_b1[i0] = d[0]; s_b1[i0+1] = d[1]; s_b1[i0+2] = d[2]; s_b1[i0+3] = d[3];
                    }
                }
                sAinv4[0*256 + tid] = g0;  sAinv4[1*256 + tid] = g1;
                sAinv4[2*256 + tid] = g2;  sAinv4[3*256 + tid] = g3;
                __syncthreads();
                // b_i = d^{i+1} raw_i + bias_i ; c = AinvF b ; h_i = d^{63-i}(sv_i - alpha c_i)
                float bvec = fmaf(s_powd[l + 1], s_b1[l], biasv);
                float c = 0.f;
#pragma unroll
                for (int jj = 0; jj < 64; ++jj)
                    c = fmaf(sAinv[jj*64 + l], rl(bvec, jj), c);
                float h = s_powd[63 - l] * fmaf(-ALPHA, c, svl);
                float4 acc = make_float4(0.f, 0.f, 0.f, 0.f);
#pragma unroll
                for (int r = 0; r < 16; ++r) {
                    float hi = rl(h, wbase + r);
                    acc.x = fmaf(hi, cur[r].x, acc.x); acc.y = fmaf(hi, cur[r].y, acc.y);
                    acc.z = fmaf(hi, cur[r].z, acc.z); acc.w = fmaf(hi, cur[r].w, acc.w);
                }
                s_part[wave][l] = acc;
                __syncthreads();
                float4 p0 = s_part[0][l], p1 = s_part[1][l], p2 = s_part[2][l], p3 = s_part[3][l];
                float d64 = s_powd[64];
                y.x = fmaf(d64, y.x, p0.x + p1.x + p2.x + p3.x);
                y.y = fmaf(d64, y.y, p0.y + p1.y + p2.y + p3.y);
                y.z = fmaf(d64, y.z, p0.z + p1.z + p2.z + p3.z);
                y.w = fmaf(d64, y.w, p0.w + p1.w + p2.w + p3.w);
                if (m + 1 < NCP) {
#pragma unroll
                    for (int r = 0; r < 16; ++r) cur[r] = nxt[r];
                }
            }
        }
        float fin[2] = { dot4v(y, y), dot4v(qn, y) };
        wave_allred_arr(fin);
        if (tid == 0) gscal[0] = fin[1] / fmaxf(sqrtf(fin[0]), 2.56e-10f);
    }
}

// ------------- Kernel 4: parallel weighted accumulation -> atomic combine -------------
__global__ __launch_bounds__(256) void accum_kernel(
    const float* __restrict__ V, const float* __restrict__ PV,
    const float* __restrict__ CS, const float* __restrict__ CPB1,
    const float* __restrict__ CPB2, const float* __restrict__ gscal,
    float* __restrict__ out, int T, int P, int NCS, int NCP)
{
    __shared__ float wc[64];
    const int b = blockIdx.x, k = threadIdx.x;
    const float* src; const float* C; int i0, realN; float decay;
    if (b < NCS)            { src = V;  C = CS;   i0 = b * 64;               realN = T; decay = S_DECAY; }
    else if (b < NCS + NCP) { src = PV; C = CPB1; i0 = (b - NCS) * 64;       realN = P; decay = P_DECAY; }
    else                    { src = PV; C = CPB2; i0 = (b - NCS - NCP) * 64; realN = P; decay = P_DECAY; }
    if (k < 64) wc[k] = powf(decay, (float)(i0 + k)) * C[i0 + k];
    __syncthreads();
    float acc = 0.f;
    for (int ii = 0; ii < 64; ++ii) {
        int i = i0 + ii;
        if (i < realN)
            acc = fmaf(wc[ii], src[(size_t)(realN - 1 - i) * DK + k], acc);
    }
    float wlev;
    if (b < NCS)            wlev = 0.2f;
    else if (b < NCS + NCP) wlev = 0.3f;
    else                    wlev = (0.5f / 256.0f) * gscal[0];
    atomicAdd(&out[k], wlev * acc);
}

extern "C" void kernel_launch(void* const* d_in, const int* in_sizes, int n_in,
                              void* d_out, int out_size, void* d_ws, size_t ws_size,
                              hipStream_t stream) {
    const float* emb = (const float*)d_in[0];
    const float* q   = (const float*)d_in[1];
    const float* Wk  = (const float*)d_in[2];
    const float* bk  = (const float*)d_in[3];
    const float* Wv  = (const float*)d_in[4];
    const float* bv  = (const float*)d_in[5];

    const int T = in_sizes[0] / D_EMB;        // 1000
    const int P = T / 5;                      // 200
    const int NCS  = (T + 63) / 64;           // 16
    const int NCP  = (P + 63) / 64;           // 4
    const int PADS = NCS * 64;                // 1024
    const int PADP = NCP * 64;                // 256

    float* ws    = (float*)d_ws;
    float* V     = ws;                               // T*256
    float* PV    = V     + (size_t)T * DK;           // PADP*256
    float* USrev = PV    + (size_t)PADP * DK;        // PADS*256
    float* UPrev = USrev + (size_t)PADS * DK;        // PADP*256
    float* UPfwd = UPrev + (size_t)PADP * DK;        // PADP*256
    float* SVv   = UPfwd + (size_t)PADP * DK;        // PADP
    float* AinvT = SVv   + PADP;                     // (NCS+2*NCP)*4096
    float* biasF = AinvT + (size_t)(NCS + 2*NCP) * 4096;  // PADP
    float* CS    = biasF + PADP;                     // PADS
    float* CPB1  = CS    + PADS;                     // PADP
    float* CPB2  = CPB1  + PADP;                     // PADP
    float* gscal = CPB2  + PADP;                     // 4

    prep_kernel<<<P / 2 + 1, 256, 0, stream>>>(emb, Wk, bk, Wv, bv,
                                               V, PV, USrev, UPrev, UPfwd, SVv,
                                               (float*)d_out, T, P, PADS, PADP);
    graminv_kernel<<<NCS + 2 * NCP, 256, 0, stream>>>(USrev, UPrev, UPfwd, SVv,
                                                      AinvT, biasF, NCS, NCP);
    solve_kernel<<<2, 256, 0, stream>>>(USrev, UPrev, UPfwd, SVv, AinvT, biasF, q,
                                        CS, CPB1, CPB2, gscal, NCS, NCP);
    accum_kernel<<<NCS + 2 * NCP, 256, 0, stream>>>(V, PV, CS, CPB1, CPB2, gscal,
                                                    (float*)d_out, T, P, NCS, NCP);
}

// Round 7
// 192.153 us; speedup vs baseline: 1.4221x; 1.4221x over previous
//
#include <hip/hip_runtime.h>
#include <hip/hip_bf16.h>

#define ALPHA   0.1f
#define S_DECAY 0.95f
#define P_DECAY 0.99f
#define D_EMB   768
#define DK      256

// ---- DPP wave-64 reduction helpers (validated rounds 1-6) ----
template<int ctrl, int row_mask>
__device__ __forceinline__ float dpp_add(float x) {
    int y = __builtin_amdgcn_update_dpp(0, __float_as_int(x), ctrl, row_mask, 0xF, true);
    return x + __int_as_float(y);
}

template<int N>
__device__ __forceinline__ void wave_allred_arr(float (&x)[N]) {
#pragma unroll
    for (int n = 0; n < N; ++n) x[n] = dpp_add<0xB1,  0xF>(x[n]);
#pragma unroll
    for (int n = 0; n < N; ++n) x[n] = dpp_add<0x4E,  0xF>(x[n]);
#pragma unroll
    for (int n = 0; n < N; ++n) x[n] = dpp_add<0x141, 0xF>(x[n]);
#pragma unroll
    for (int n = 0; n < N; ++n) x[n] = dpp_add<0x140, 0xF>(x[n]);
#pragma unroll
    for (int n = 0; n < N; ++n) x[n] = dpp_add<0x142, 0xA>(x[n]);
#pragma unroll
    for (int n = 0; n < N; ++n) x[n] = dpp_add<0x143, 0xC>(x[n]);
#pragma unroll
    for (int n = 0; n < N; ++n)
        x[n] = __int_as_float(__builtin_amdgcn_readlane(__float_as_int(x[n]), 63));
}

__device__ __forceinline__ float dot4v(const float4& a, const float4& b) {
    float t0 = a.x * b.x; t0 = fmaf(a.y, b.y, t0);
    float t1 = a.z * b.z; t1 = fmaf(a.w, b.w, t1);
    return t0 + t1;
}

__device__ __forceinline__ float rl(float x, int lane) {
    return __int_as_float(__builtin_amdgcn_readlane(__float_as_int(x), lane));
}

// ---------------- Kernel 1: GEMM, 4 rows x ONE matrix per block (500 blocks) ----------------
// bid&1: 0 = K (+ row norms -> USrev), 1 = V. Extra block zeroes USrev pad + out.
__global__ __launch_bounds__(256) void prep_kernel(
    const float* __restrict__ emb,
    const float* __restrict__ Wk, const float* __restrict__ bk,
    const float* __restrict__ Wv, const float* __restrict__ bv,
    float* __restrict__ K, float* __restrict__ V, float* __restrict__ USrev,
    float* __restrict__ out, int T)
{
    const int tid = threadIdx.x;
    const int bid = blockIdx.x;
    const int NBLK = (T / 4) * 2;                 // 500
    if (bid >= NBLK) {
        const int PADS = ((T + 63) / 64) * 64;
        for (int i = tid; i < (PADS - T) * DK; i += 256) USrev[(size_t)T * DK + i] = 0.f;
        out[tid] = 0.f;
        return;
    }
    const int mat = bid & 1;
    const int r0  = (bid >> 1) * 4;

    __shared__ float se[4][D_EMB];
    __shared__ float s_red[4][4];

    const float4* emb4 = reinterpret_cast<const float4*>(emb);
#pragma unroll
    for (int r = 0; r < 4; ++r) {
        if (tid < D_EMB / 4)
            reinterpret_cast<float4*>(se[r])[tid] = emb4[(size_t)(r0 + r) * (D_EMB / 4) + tid];
    }
    __syncthreads();

    const float* Wp = mat ? Wv : Wk;
    const float* bp = mat ? bv : bk;
    const int j = tid;

    float a0 = 0.f, a1 = 0.f, a2 = 0.f, a3 = 0.f;
    // depth-2 W pipeline
    float c0 = Wp[j],        c1 = Wp[j + DK],     c2 = Wp[j + 2*DK], c3 = Wp[j + 3*DK];
    float p0 = Wp[j + 4*DK], p1 = Wp[j + 5*DK],   p2 = Wp[j + 6*DK], p3 = Wp[j + 7*DK];

    for (int d = 0; d < D_EMB; d += 4) {
        int dn = d + 8; if (dn >= D_EMB) dn = 0;
        const float* wn = Wp + (size_t)dn * DK + j;
        float n0 = wn[0], n1 = wn[DK], n2 = wn[2*DK], n3 = wn[3*DK];

        float4 e0 = *reinterpret_cast<const float4*>(&se[0][d]);
        float4 e1 = *reinterpret_cast<const float4*>(&se[1][d]);
        float4 e2 = *reinterpret_cast<const float4*>(&se[2][d]);
        float4 e3 = *reinterpret_cast<const float4*>(&se[3][d]);

        a0 = fmaf(e0.x, c0, a0); a0 = fmaf(e0.y, c1, a0);
        a0 = fmaf(e0.z, c2, a0); a0 = fmaf(e0.w, c3, a0);
        a1 = fmaf(e1.x, c0, a1); a1 = fmaf(e1.y, c1, a1);
        a1 = fmaf(e1.z, c2, a1); a1 = fmaf(e1.w, c3, a1);
        a2 = fmaf(e2.x, c0, a2); a2 = fmaf(e2.y, c1, a2);
        a2 = fmaf(e2.z, c2, a2); a2 = fmaf(e2.w, c3, a2);
        a3 = fmaf(e3.x, c0, a3); a3 = fmaf(e3.y, c1, a3);
        a3 = fmaf(e3.z, c2, a3); a3 = fmaf(e3.w, c3, a3);

        c0 = p0; c1 = p1; c2 = p2; c3 = p3;
        p0 = n0; p1 = n1; p2 = n2; p3 = n3;
    }

    float bj = bp[j];
    float o0 = a0 + bj, o1 = a1 + bj, o2 = a2 + bj, o3 = a3 + bj;
    float* dst = mat ? V : K;
    dst[(size_t)(r0 + 0) * DK + j] = o0;
    dst[(size_t)(r0 + 1) * DK + j] = o1;
    dst[(size_t)(r0 + 2) * DK + j] = o2;
    dst[(size_t)(r0 + 3) * DK + j] = o3;

    if (mat == 0) {
        const int wave = tid >> 6, l = tid & 63;
        float red[4] = { o0*o0, o1*o1, o2*o2, o3*o3 };
        wave_allred_arr(red);
        if (l == 0) {
            s_red[wave][0] = red[0]; s_red[wave][1] = red[1];
            s_red[wave][2] = red[2]; s_red[wave][3] = red[3];
        }
        __syncthreads();
        float t0 = s_red[0][0] + s_red[1][0] + s_red[2][0] + s_red[3][0];
        float t1 = s_red[0][1] + s_red[1][1] + s_red[2][1] + s_red[3][1];
        float t2 = s_red[0][2] + s_red[1][2] + s_red[2][2] + s_red[3][2];
        float t3 = s_red[0][3] + s_red[1][3] + s_red[2][3] + s_red[3][3];
        USrev[(size_t)(T - 1 - (r0 + 0)) * DK + j] = o0 * (1.0f / fmaxf(sqrtf(t0), 1e-12f));
        USrev[(size_t)(T - 1 - (r0 + 1)) * DK + j] = o1 * (1.0f / fmaxf(sqrtf(t1), 1e-12f));
        USrev[(size_t)(T - 1 - (r0 + 2)) * DK + j] = o2 * (1.0f / fmaxf(sqrtf(t2), 1e-12f));
        USrev[(size_t)(T - 1 - (r0 + 3)) * DK + j] = o3 * (1.0f / fmaxf(sqrtf(t3), 1e-12f));
    }
}

// ------------- Kernel 2: build U rows (incl. paragraph means) + LDS gram + inversion -------------
// 24 blocks: [0,NCS)=sentence (load USrev), [NCS,NCS+NCP)=paraBackward (compute UPrev),
// [NCS+NCP,..)=paraForward (compute UPfwd + PV + SVv + biasF).
__global__ __launch_bounds__(256) void graminv_kernel(
    const float* __restrict__ K, const float* __restrict__ V,
    const float* __restrict__ USrev,
    float* __restrict__ UPrev, float* __restrict__ UPfwd,
    float* __restrict__ PV, float* __restrict__ SVv,
    float* __restrict__ AinvT, float* __restrict__ biasF,
    int P, int NCS, int NCP)
{
    __shared__ float sU[64 * 257];
    __shared__ float sA[64 * 65];
    __shared__ float sX[64 * 65];
    __shared__ float s_sv[64];
    __shared__ float s_pd[64];
    const int tid = threadIdx.x, wv = tid >> 6, l = tid & 63;
    const int bid = blockIdx.x;
    int type, m;
    if (bid < NCS)            { type = 0; m = bid; }
    else if (bid < NCS + NCP) { type = 1; m = bid - NCS; }
    else                      { type = 2; m = bid - NCS - NCP; }

    if (tid < 64) s_pd[tid] = powf(P_DECAY, (float)tid);

    // --- phase A: fill sU rows (64 x 256, row stride 257 words) ---
    if (type == 0) {
        const float4* U4 = reinterpret_cast<const float4*>(USrev) + (size_t)m * 4096;
        for (int idx = tid; idx < 4096; idx += 256) {
            float4 t = U4[idx];
            int row = idx >> 6, c4 = (idx & 63) << 2;
            float* b = &sU[row * 257 + c4];
            b[0] = t.x; b[1] = t.y; b[2] = t.z; b[3] = t.w;
        }
    } else if (type == 1) {
        const float4* K4 = reinterpret_cast<const float4*>(K);
        for (int ii = 0; ii < 16; ++ii) {
            int i = wv * 16 + ii;
            int p = P - 1 - (64 * m + i);
            float4 u = make_float4(0.f, 0.f, 0.f, 0.f);
            if (p >= 0) {
                float4 pk = make_float4(0.f, 0.f, 0.f, 0.f);
#pragma unroll
                for (int s = 0; s < 5; ++s) {
                    float4 k4 = K4[(size_t)(5 * p + s) * 64 + l];
                    pk.x += k4.x; pk.y += k4.y; pk.z += k4.z; pk.w += k4.w;
                }
                pk.x *= 0.2f; pk.y *= 0.2f; pk.z *= 0.2f; pk.w *= 0.2f;
                float red[1] = { dot4v(pk, pk) };
                wave_allred_arr(red);
                float inv = 1.0f / fmaxf(sqrtf(red[0]), 1e-12f);
                u = make_float4(pk.x * inv, pk.y * inv, pk.z * inv, pk.w * inv);
            }
            float* b = &sU[i * 257 + 4 * l];
            b[0] = u.x; b[1] = u.y; b[2] = u.z; b[3] = u.w;
            reinterpret_cast<float4*>(UPrev)[(size_t)(64 * m + i) * 64 + l] = u;
        }
    } else {
        const float4* K4 = reinterpret_cast<const float4*>(K);
        const float4* V4 = reinterpret_cast<const float4*>(V);
        for (int ii = 0; ii < 16; ++ii) {
            int i = wv * 16 + ii;
            int p = 64 * m + i;
            float4 u = make_float4(0.f, 0.f, 0.f, 0.f);
            float sv = 0.f;
            if (p < P) {
                float4 pk = make_float4(0.f, 0.f, 0.f, 0.f);
                float4 pv = make_float4(0.f, 0.f, 0.f, 0.f);
#pragma unroll
                for (int s = 0; s < 5; ++s) {
                    float4 k4 = K4[(size_t)(5 * p + s) * 64 + l];
                    float4 v4 = V4[(size_t)(5 * p + s) * 64 + l];
                    pk.x += k4.x; pk.y += k4.y; pk.z += k4.z; pk.w += k4.w;
                    pv.x += v4.x; pv.y += v4.y; pv.z += v4.z; pv.w += v4.w;
                }
                pk.x *= 0.2f; pk.y *= 0.2f; pk.z *= 0.2f; pk.w *= 0.2f;
                pv.x *= 0.2f; pv.y *= 0.2f; pv.z *= 0.2f; pv.w *= 0.2f;
                reinterpret_cast<float4*>(PV)[(size_t)p * 64 + l] = pv;
                float red[2] = { dot4v(pk, pk), pv.x + pv.y + pv.z + pv.w };
                wave_allred_arr(red);
                float inv = 1.0f / fmaxf(sqrtf(red[0]), 1e-12f);
                u = make_float4(pk.x * inv, pk.y * inv, pk.z * inv, pk.w * inv);
                sv = red[1];
            }
            float* b = &sU[i * 257 + 4 * l];
            b[0] = u.x; b[1] = u.y; b[2] = u.z; b[3] = u.w;
            reinterpret_cast<float4*>(UPfwd)[(size_t)(64 * m + i) * 64 + l] = u;
            if (l == 0) { s_sv[i] = sv; SVv[64 * m + i] = sv; }
        }
    }
    __syncthreads();

    // --- phase B: gram 4x4 register tile per thread, scalar LDS reads (2-way, free) ---
    const int tr = tid & 15, tcg = tid >> 4;
    const int i0 = tr * 4, j0 = tcg * 4;
    float g00=0,g01=0,g02=0,g03=0, g10=0,g11=0,g12=0,g13=0;
    float g20=0,g21=0,g22=0,g23=0, g30=0,g31=0,g32=0,g33=0;
    for (int k = 0; k < 256; ++k) {
        float aa0 = sU[(i0    ) * 257 + k];
        float aa1 = sU[(i0 + 1) * 257 + k];
        float aa2 = sU[(i0 + 2) * 257 + k];
        float aa3 = sU[(i0 + 3) * 257 + k];
        float bb0 = sU[(j0    ) * 257 + k];
        float bb1 = sU[(j0 + 1) * 257 + k];
        float bb2 = sU[(j0 + 2) * 257 + k];
        float bb3 = sU[(j0 + 3) * 257 + k];
        g00 = fmaf(aa0, bb0, g00); g01 = fmaf(aa0, bb1, g01);
        g02 = fmaf(aa0, bb2, g02); g03 = fmaf(aa0, bb3, g03);
        g10 = fmaf(aa1, bb0, g10); g11 = fmaf(aa1, bb1, g11);
        g12 = fmaf(aa1, bb2, g12); g13 = fmaf(aa1, bb3, g13);
        g20 = fmaf(aa2, bb0, g20); g21 = fmaf(aa2, bb1, g21);
        g22 = fmaf(aa2, bb2, g22); g23 = fmaf(aa2, bb3, g23);
        g30 = fmaf(aa3, bb0, g30); g31 = fmaf(aa3, bb1, g31);
        g32 = fmaf(aa3, bb2, g32); g33 = fmaf(aa3, bb3, g33);
    }
    float gt[4][4] = { {g00,g01,g02,g03}, {g10,g11,g12,g13},
                       {g20,g21,g22,g23}, {g30,g31,g32,g33} };
#pragma unroll
    for (int r = 0; r < 4; ++r)
#pragma unroll
        for (int c = 0; c < 4; ++c) {
            int gi = i0 + r, gj = j0 + c;
            float val = 0.f;
            if (gj < gi) {
                val = ALPHA * gt[r][c];
                if (type == 2) val *= s_pd[gi - gj];
            }
            sA[gi * 65 + gj] = val;
        }
    __syncthreads();

    // --- bias (type 2): bias_i = sum_j g_ij * sv_j = (1/alpha) * sum_j A_ij sv_j ---
    if (type == 2 && wv == 0) {
        float dotb = 0.f;
#pragma unroll
        for (int jj = 0; jj < 64; ++jj)
            dotb = fmaf(sA[l * 65 + jj], s_sv[jj], dotb);
        biasF[m * 64 + l] = dotb * (1.0f / ALPHA);
    }

    // --- phase C: X = (I+A)^{-1}, wave-staged forward substitution (validated r6) ---
    const int base = wv * 16;
    float x[16];
#pragma unroll
    for (int r = 0; r < 16; ++r) x[r] = (base + r == l) ? 1.f : 0.f;
    for (int s = 0; s < 4; ++s) {
        if (wv == s) {
#pragma unroll
            for (int i = 1; i < 16; ++i)
#pragma unroll
                for (int jj = 0; jj < 16; ++jj)
                    if (jj < i)
                        x[i] = fmaf(-sA[(base + i) * 65 + (base + jj)], x[jj], x[i]);
#pragma unroll
            for (int r = 0; r < 16; ++r) sX[(base + r) * 65 + l] = x[r];
        }
        __syncthreads();
        if (wv > s) {
#pragma unroll
            for (int i = 0; i < 16; ++i) {
                float xi = sX[(s * 16 + i) * 65 + l];
#pragma unroll
                for (int r = 0; r < 16; ++r)
                    x[r] = fmaf(-sA[(base + r) * 65 + (s * 16 + i)], xi, x[r]);
            }
        }
    }
    __syncthreads();
    float* dstA = AinvT + (size_t)bid * 4096;
    for (int idx = tid; idx < 4096; idx += 256) {
        int jcol = idx >> 6, irow = idx & 63;
        dstA[idx] = sX[irow * 65 + jcol];
    }
}

// ------------- Kernel 3: solver, 2 concurrent blocks, parallel phase-2 via Ainv (r6, passed) -------------
__global__ __launch_bounds__(256) void solve_kernel(
    const float* __restrict__ USrev, const float* __restrict__ UPrev,
    const float* __restrict__ UPfwd, const float* __restrict__ SVv,
    const float* __restrict__ AinvT, const float* __restrict__ biasF,
    const float* __restrict__ q,
    float* __restrict__ CS, float* __restrict__ CPB1, float* __restrict__ CPB2,
    float* __restrict__ gscal, int NCS, int NCP)
{
    __shared__ float s_b1[64], s_b2[64];
    __shared__ float4 s_part[4][64], s_part2[4][64];
    __shared__ float sAinv[4096];
    __shared__ float s_powd[65];
    const int tid = threadIdx.x, wave = tid >> 6, l = tid & 63;
    const int wbase = wave * 16;
    if (tid <= 64) s_powd[tid] = powf(P_DECAY, (float)tid);

    float4 q4 = reinterpret_cast<const float4*>(q)[l];
    float qs[1] = { dot4v(q4, q4) };
    wave_allred_arr(qs);
    float qinv = 1.0f / fmaxf(sqrtf(qs[0]), 1e-12f);
    float4 qn = make_float4(q4.x * qinv, q4.y * qinv, q4.z * qinv, q4.w * qinv);
    __syncthreads();

    const float4* G4 = reinterpret_cast<const float4*>(AinvT);
    float4* sAinv4 = reinterpret_cast<float4*>(sAinv);

    if (blockIdx.x == 0) {
        float4 w1 = qn;
        const float4* U4 = reinterpret_cast<const float4*>(USrev);
        float4 cur[16];
#pragma unroll
        for (int r = 0; r < 16; ++r) cur[r] = U4[(size_t)(wbase + r) * 64 + l];
        for (int m = 0; m < NCS; ++m) {
            float4 g0 = G4[(size_t)m * 1024 + 0*256 + tid];
            float4 g1 = G4[(size_t)m * 1024 + 1*256 + tid];
            float4 g2 = G4[(size_t)m * 1024 + 2*256 + tid];
            float4 g3 = G4[(size_t)m * 1024 + 3*256 + tid];
            float4 nxt[16];
            if (m + 1 < NCS) {
                const float4* Un = U4 + (size_t)(m + 1) * 64 * 64;
#pragma unroll
                for (int r = 0; r < 16; ++r) nxt[r] = Un[(size_t)(wbase + r) * 64 + l];
            }
#pragma unroll
            for (int g = 0; g < 4; ++g) {
                float d[4];
#pragma unroll
                for (int r = 0; r < 4; ++r) d[r] = dot4v(cur[g*4 + r], w1);
                wave_allred_arr(d);
                if (l == 0) {
                    int i0 = wbase + g*4;
                    s_b1[i0] = d[0]; s_b1[i0+1] = d[1]; s_b1[i0+2] = d[2]; s_b1[i0+3] = d[3];
                }
            }
            sAinv4[0*256 + tid] = g0;  sAinv4[1*256 + tid] = g1;
            sAinv4[2*256 + tid] = g2;  sAinv4[3*256 + tid] = g3;
            __syncthreads();
            float bv = s_b1[l];
            float c = 0.f;
#pragma unroll
            for (int jj = 0; jj < 64; ++jj)
                c = fmaf(sAinv[jj*64 + l], rl(bv, jj), c);
            if (wave == 0) CS[m * 64 + l] = c;
            float4 acc = make_float4(0.f, 0.f, 0.f, 0.f);
#pragma unroll
            for (int r = 0; r < 16; ++r) {
                float ci = rl(c, wbase + r);
                acc.x = fmaf(ci, cur[r].x, acc.x); acc.y = fmaf(ci, cur[r].y, acc.y);
                acc.z = fmaf(ci, cur[r].z, acc.z); acc.w = fmaf(ci, cur[r].w, acc.w);
            }
            s_part[wave][l] = acc;
            __syncthreads();
            float4 p0 = s_part[0][l], p1 = s_part[1][l], p2 = s_part[2][l], p3 = s_part[3][l];
            w1.x = fmaf(-ALPHA, p0.x + p1.x + p2.x + p3.x, w1.x);
            w1.y = fmaf(-ALPHA, p0.y + p1.y + p2.y + p3.y, w1.y);
            w1.z = fmaf(-ALPHA, p0.z + p1.z + p2.z + p3.z, w1.z);
            w1.w = fmaf(-ALPHA, p0.w + p1.w + p2.w + p3.w, w1.w);
            if (m + 1 < NCS) {
#pragma unroll
                for (int r = 0; r < 16; ++r) cur[r] = nxt[r];
            }
        }
    } else {
        {
            float4 w1 = qn;
            float4 w2 = make_float4(1.f, 1.f, 1.f, 1.f);
            const float4* U4 = reinterpret_cast<const float4*>(UPrev);
            float4 cur[16];
#pragma unroll
            for (int r = 0; r < 16; ++r) cur[r] = U4[(size_t)(wbase + r) * 64 + l];
            for (int m = 0; m < NCP; ++m) {
                size_t gb = (size_t)(NCS + m) * 1024;
                float4 g0 = G4[gb + 0*256 + tid];
                float4 g1 = G4[gb + 1*256 + tid];
                float4 g2 = G4[gb + 2*256 + tid];
                float4 g3 = G4[gb + 3*256 + tid];
                float4 nxt[16];
                if (m + 1 < NCP) {
                    const float4* Un = U4 + (size_t)(m + 1) * 64 * 64;
#pragma unroll
                    for (int r = 0; r < 16; ++r) nxt[r] = Un[(size_t)(wbase + r) * 64 + l];
                }
#pragma unroll
                for (int g = 0; g < 4; ++g) {
                    float d[8];
#pragma unroll
                    for (int r = 0; r < 4; ++r) {
                        d[r]     = dot4v(cur[g*4 + r], w1);
                        d[4 + r] = dot4v(cur[g*4 + r], w2);
                    }
                    wave_allred_arr(d);
                    if (l == 0) {
                        int i0 = wbase + g*4;
#pragma unroll
                        for (int r = 0; r < 4; ++r) { s_b1[i0+r] = d[r]; s_b2[i0+r] = d[4+r]; }
                    }
                }
                sAinv4[0*256 + tid] = g0;  sAinv4[1*256 + tid] = g1;
                sAinv4[2*256 + tid] = g2;  sAinv4[3*256 + tid] = g3;
                __syncthreads();
                float bv1 = s_b1[l], bv2 = s_b2[l];
                float c1 = 0.f, c2 = 0.f;
#pragma unroll
                for (int jj = 0; jj < 64; ++jj) {
                    float a = sAinv[jj*64 + l];
                    c1 = fmaf(a, rl(bv1, jj), c1);
                    c2 = fmaf(a, rl(bv2, jj), c2);
                }
                if (wave == 0) { CPB1[m * 64 + l] = c1; CPB2[m * 64 + l] = c2; }
                float4 a1 = make_float4(0.f,0.f,0.f,0.f), a2 = make_float4(0.f,0.f,0.f,0.f);
#pragma unroll
                for (int r = 0; r < 16; ++r) {
                    float x1 = rl(c1, wbase + r), x2 = rl(c2, wbase + r);
                    a1.x = fmaf(x1, cur[r].x, a1.x); a1.y = fmaf(x1, cur[r].y, a1.y);
                    a1.z = fmaf(x1, cur[r].z, a1.z); a1.w = fmaf(x1, cur[r].w, a1.w);
                    a2.x = fmaf(x2, cur[r].x, a2.x); a2.y = fmaf(x2, cur[r].y, a2.y);
                    a2.z = fmaf(x2, cur[r].z, a2.z); a2.w = fmaf(x2, cur[r].w, a2.w);
                }
                s_part[wave][l] = a1; s_part2[wave][l] = a2;
                __syncthreads();
                float4 p0 = s_part[0][l], p1 = s_part[1][l], p2 = s_part[2][l], p3 = s_part[3][l];
                w1.x = fmaf(-ALPHA, p0.x+p1.x+p2.x+p3.x, w1.x);
                w1.y = fmaf(-ALPHA, p0.y+p1.y+p2.y+p3.y, w1.y);
                w1.z = fmaf(-ALPHA, p0.z+p1.z+p2.z+p3.z, w1.z);
                w1.w = fmaf(-ALPHA, p0.w+p1.w+p2.w+p3.w, w1.w);
                float4 r0 = s_part2[0][l], r1 = s_part2[1][l], r2 = s_part2[2][l], r3 = s_part2[3][l];
                w2.x = fmaf(-ALPHA, r0.x+r1.x+r2.x+r3.x, w2.x);
                w2.y = fmaf(-ALPHA, r0.y+r1.y+r2.y+r3.y, w2.y);
                w2.z = fmaf(-ALPHA, r0.z+r1.z+r2.z+r3.z, w2.z);
                w2.w = fmaf(-ALPHA, r0.w+r1.w+r2.w+r3.w, w2.w);
                if (m + 1 < NCP) {
#pragma unroll
                    for (int r = 0; r < 16; ++r) cur[r] = nxt[r];
                }
            }
        }
        __syncthreads();
        float4 y = make_float4(0.f, 0.f, 0.f, 0.f);
        {
            const float4* U4 = reinterpret_cast<const float4*>(UPfwd);
            float4 cur[16];
#pragma unroll
            for (int r = 0; r < 16; ++r) cur[r] = U4[(size_t)(wbase + r) * 64 + l];
            for (int m = 0; m < NCP; ++m) {
                size_t gb = (size_t)(NCS + NCP + m) * 1024;
                float4 g0 = G4[gb + 0*256 + tid];
                float4 g1 = G4[gb + 1*256 + tid];
                float4 g2 = G4[gb + 2*256 + tid];
                float4 g3 = G4[gb + 3*256 + tid];
                float biasv = biasF[m * 64 + l];
                float svl   = SVv[m * 64 + l];
                float4 nxt[16];
                if (m + 1 < NCP) {
                    const float4* Un = U4 + (size_t)(m + 1) * 64 * 64;
#pragma unroll
                    for (int r = 0; r < 16; ++r) nxt[r] = Un[(size_t)(wbase + r) * 64 + l];
                }
#pragma unroll
                for (int g = 0; g < 4; ++g) {
                    float d[4];
#pragma unroll
                    for (int r = 0; r < 4; ++r) d[r] = dot4v(cur[g*4 + r], y);
                    wave_allred_arr(d);
                    if (l == 0) {
                        int i0 = wbase + g*4;
                        s_b1[i0] = d[0]; s_b1[i0+1] = d[1]; s_b1[i0+2] = d[2]; s_b1[i0+3] = d[3];
                    }
                }
                sAinv4[0*256 + tid] = g0;  sAinv4[1*256 + tid] = g1;
                sAinv4[2*256 + tid] = g2;  sAinv4[3*256 + tid] = g3;
                __syncthreads();
                float bvec = fmaf(s_powd[l + 1], s_b1[l], biasv);
                float c = 0.f;
#pragma unroll
                for (int jj = 0; jj < 64; ++jj)
                    c = fmaf(sAinv[jj*64 + l], rl(bvec, jj), c);
                float h = s_powd[63 - l] * fmaf(-ALPHA, c, svl);
                float4 acc = make_float4(0.f, 0.f, 0.f, 0.f);
#pragma unroll
                for (int r = 0; r < 16; ++r) {
                    float hi = rl(h, wbase + r);
                    acc.x = fmaf(hi, cur[r].x, acc.x); acc.y = fmaf(hi, cur[r].y, acc.y);
                    acc.z = fmaf(hi, cur[r].z, acc.z); acc.w = fmaf(hi, cur[r].w, acc.w);
                }
                s_part[wave][l] = acc;
                __syncthreads();
                float4 p0 = s_part[0][l], p1 = s_part[1][l], p2 = s_part[2][l], p3 = s_part[3][l];
                float d64 = s_powd[64];
                y.x = fmaf(d64, y.x, p0.x + p1.x + p2.x + p3.x);
                y.y = fmaf(d64, y.y, p0.y + p1.y + p2.y + p3.y);
                y.z = fmaf(d64, y.z, p0.z + p1.z + p2.z + p3.z);
                y.w = fmaf(d64, y.w, p0.w + p1.w + p2.w + p3.w);
                if (m + 1 < NCP) {
#pragma unroll
                    for (int r = 0; r < 16; ++r) cur[r] = nxt[r];
                }
            }
        }
        float fin[2] = { dot4v(y, y), dot4v(qn, y) };
        wave_allred_arr(fin);
        if (tid == 0) gscal[0] = fin[1] / fmaxf(sqrtf(fin[0]), 2.56e-10f);
    }
}

// ------------- Kernel 4: parallel weighted accumulation -> atomic combine -------------
__global__ __launch_bounds__(256) void accum_kernel(
    const float* __restrict__ V, const float* __restrict__ PV,
    const float* __restrict__ CS, const float* __restrict__ CPB1,
    const float* __restrict__ CPB2, const float* __restrict__ gscal,
    float* __restrict__ out, int T, int P, int NCS, int NCP)
{
    __shared__ float wc[64];
    const int b = blockIdx.x, k = threadIdx.x;
    const float* src; const float* C; int i0, realN; float decay;
    if (b < NCS)            { src = V;  C = CS;   i0 = b * 64;               realN = T; decay = S_DECAY; }
    else if (b < NCS + NCP) { src = PV; C = CPB1; i0 = (b - NCS) * 64;       realN = P; decay = P_DECAY; }
    else                    { src = PV; C = CPB2; i0 = (b - NCS - NCP) * 64; realN = P; decay = P_DECAY; }
    if (k < 64) wc[k] = powf(decay, (float)(i0 + k)) * C[i0 + k];
    __syncthreads();
    float acc = 0.f;
    for (int ii = 0; ii < 64; ++ii) {
        int i = i0 + ii;
        if (i < realN)
            acc = fmaf(wc[ii], src[(size_t)(realN - 1 - i) * DK + k], acc);
    }
    float wlev;
    if (b < NCS)            wlev = 0.2f;
    else if (b < NCS + NCP) wlev = 0.3f;
    else                    wlev = (0.5f / 256.0f) * gscal[0];
    atomicAdd(&out[k], wlev * acc);
}

extern "C" void kernel_launch(void* const* d_in, const int* in_sizes, int n_in,
                              void* d_out, int out_size, void* d_ws, size_t ws_size,
                              hipStream_t stream) {
    const float* emb = (const float*)d_in[0];
    const float* q   = (const float*)d_in[1];
    const float* Wk  = (const float*)d_in[2];
    const float* bk  = (const float*)d_in[3];
    const float* Wv  = (const float*)d_in[4];
    const float* bv  = (const float*)d_in[5];

    const int T = in_sizes[0] / D_EMB;        // 1000
    const int P = T / 5;                      // 200
    const int NCS  = (T + 63) / 64;           // 16
    const int NCP  = (P + 63) / 64;           // 4
    const int PADS = NCS * 64;                // 1024
    const int PADP = NCP * 64;                // 256

    float* ws    = (float*)d_ws;
    float* K     = ws;                               // T*256
    float* V     = K     + (size_t)T * DK;           // T*256
    float* PV    = V     + (size_t)T * DK;           // PADP*256
    float* USrev = PV    + (size_t)PADP * DK;        // PADS*256
    float* UPrev = USrev + (size_t)PADS * DK;        // PADP*256
    float* UPfwd = UPrev + (size_t)PADP * DK;        // PADP*256
    float* SVv   = UPfwd + (size_t)PADP * DK;        // PADP
    float* AinvT = SVv   + PADP;                     // (NCS+2*NCP)*4096
    float* biasF = AinvT + (size_t)(NCS + 2*NCP) * 4096;  // PADP
    float* CS    = biasF + PADP;                     // PADS
    float* CPB1  = CS    + PADS;                     // PADP
    float* CPB2  = CPB1  + PADP;                     // PADP
    float* gscal = CPB2  + PADP;                     // 4

    prep_kernel<<<(T / 4) * 2 + 1, 256, 0, stream>>>(emb, Wk, bk, Wv, bv,
                                                     K, V, USrev, (float*)d_out, T);
    graminv_kernel<<<NCS + 2 * NCP, 256, 0, stream>>>(K, V, USrev, UPrev, UPfwd,
                                                      PV, SVv, AinvT, biasF, P, NCS, NCP);
    solve_kernel<<<2, 256, 0, stream>>>(USrev, UPrev, UPfwd, SVv, AinvT, biasF, q,
                                        CS, CPB1, CPB2, gscal, NCS, NCP);
    accum_kernel<<<NCS + 2 * NCP, 256, 0, stream>>>(V, PV, CS, CPB1, CPB2, gscal,
                                                    (float*)d_out, T, P, NCS, NCP);
}